// Round 9
// baseline (286.225 us; speedup 1.0000x reference)
//
#include <hip/hip_runtime.h>

// ---------------------------------------------------------------------------
// UpThreeOffsetsConvShareWeights v10: N-split waves, sync-free main loop.
//
// Same algebra (separable deform offsets -> per-phase 2x2x2-tap conv == GEMM
// M=spatial x N=96 x K=512; fused K=96 combine GEMM), C^T convention
// (mfma(W_frag, x_frag), lane&15 = spatial col), 16x16x32 MFMA, channel-
// permuted W_sw/W2_sw (v8-proven k_prep, byte-identical), x direct-from-L2
// with OOB->zero-tail redirect, full-line float2 stores.
//
// v9 lesson: weights must be read once per BLOCK (L2 traffic), x coalesced.
// v5-v8 lesson: per-chunk vmcnt(0)+barrier lockstep caps at ~46us, all pipes
// <25%. v10 gets both without either mechanism:
//  * 6 waves/block; wave n owns ntile n (16 of 96 channels). Each weight
//    byte read by exactly ONE wave -> block weight traffic = 192KB (as v8's
//    LDS ring) with NO LDS staging and NO barriers/asm in the main loop.
//  * per wave k-step: 1 weight uint4 + 8 x uint4 + 8 MFMA; acc = 32 VGPR ->
//    deep compiler pipelining; x shared across waves via L1 (8KB/kstep).
//  * combine: 3-barrier epilogue through a 26.6KB LDS act buffer written
//    directly in the combine-B k2 order (v8's proven permutation):
//    col = 32*(n>>1) + 8*hi + 4*(n&1) + r. Waves 0-3 read uint4 fragments,
//    12 MFMAs, float2 stores.
//  * block = M=128 (8x,4y,4z) x (a,bph); grid 1024, phase-siblings co-XCD.
// ---------------------------------------------------------------------------

typedef __bf16 bf16x8 __attribute__((ext_vector_type(8)));
typedef float f32x4 __attribute__((ext_vector_type(4)));

__device__ inline unsigned short f2bf(float f) {
  unsigned int u = __float_as_uint(f);
  u += 0x7FFFu + ((u >> 16) & 1u);
  return (unsigned short)(u >> 16);
}

__device__ inline bf16x8 bc16(uint4 v) { return __builtin_bit_cast(bf16x8, v); }

__device__ inline unsigned cvtpk(float lo, float hi) {
  unsigned r;
  asm("v_cvt_pk_bf16_f32 %0, %1, %2" : "=v"(r) : "v"(lo), "v"(hi));
  return r;
}

__device__ inline float ucoef(int abit, int k, int jbit, float alpha) {
  if (abit == 0) return (k == 0) ? (jbit ? alpha : 1.f - alpha) : (jbit ? 1.f : 0.f);
  return (k == 2) ? (jbit ? 1.f - alpha : alpha) : (jbit ? 0.f : 1.f);
}

// xT2 geometry: 4 regions (16-ch groups), each 32768 sp * 32 B + 128 B zero tail.
#define XREG_USH 524352   // region stride in ushorts (1,048,704 B)
#define XZERO_B 1048576u  // zero-tail byte offset within a region

// ---------------- K0: all preprocessing in one kernel (2049 blocks) ---------
// (byte-identical to v8's proven k_prep)
__global__ void k_prep(const float* __restrict__ x, unsigned short* __restrict__ xT2,
                       const float* __restrict__ w_def, const float* __restrict__ bn1_g,
                       const float* __restrict__ bn1_v, unsigned short* __restrict__ W_sw,
                       const float* __restrict__ w_comb, const float* __restrict__ b_comb,
                       const float* __restrict__ bn2_g, const float* __restrict__ bn2_b,
                       const float* __restrict__ bn2_m, const float* __restrict__ bn2_v,
                       const float* __restrict__ b_def, const float* __restrict__ bn1_b,
                       const float* __restrict__ bn1_m, unsigned short* __restrict__ W2_sw,
                       float* __restrict__ bias1, float* __restrict__ bias2) {
  __shared__ unsigned short t[64][65];
  int bid = blockIdx.x;
  if (bid < 512) {
    int s0 = bid * 64;
    int lane = threadIdx.x & 63;
    int grp = threadIdx.x >> 6;
#pragma unroll
    for (int c = grp; c < 64; c += 4)
      t[c][lane] = f2bf(x[c * 32768 + s0 + lane]);
    __syncthreads();
    int q = lane >> 4, e = lane & 15;  // channel = 16q + e
#pragma unroll
    for (int s = grp; s < 64; s += 4)
      xT2[q * XREG_USH + (size_t)(s0 + s) * 16 + e] = t[lane][s];
  } else if (bid < 2048) {
    int e = (bid - 512) * 256 + threadIdx.x;  // < 393216
    int j = e & 7;
    int lane = (e >> 3) & 63;
    int idx = e >> 9;          // (p*16 + kstep)*6 + ntile
    int ntile = idx % 6;
    int idx2 = idx / 6;
    int kstep = idx2 & 15;
    int p = idx2 >> 4;
    int n = ntile * 16 + (lane & 15);
    int o = n & 31, br = n >> 5;
    int k = (kstep << 5) + ((lane >> 4) << 3) + j;
    int tap = k >> 6, ch = k & 63;
    int jz = (tap >> 2) & 1, jy = (tap >> 1) & 1, jx = tap & 1;
    int a = (p >> 2) & 1, b = (p >> 1) & 1, cp = p & 1;
    float alpha = (br == 0) ? 0.f : ((br == 1) ? 0.4f : 0.7f);
    const float* wb = w_def + (o * 64 + ch) * 27;
    float sum = 0.f;
    for (int kz = 0; kz < 3; ++kz) {
      float uz = ucoef(a, kz, jz, alpha);
      if (uz == 0.f) continue;
      for (int ky = 0; ky < 3; ++ky) {
        float uy = ucoef(b, ky, jy, alpha);
        if (uy == 0.f) continue;
        float uzy = uz * uy;
        for (int kx = 0; kx < 3; ++kx) {
          float ux = ucoef(cp, kx, jx, alpha);
          if (ux != 0.f) sum += wb[kz * 9 + ky * 3 + kx] * uzy * ux;
        }
      }
    }
    float s1 = bn1_g[o] * rsqrtf(bn1_v[o] + 1e-5f);
    W_sw[e] = f2bf(sum * s1);
  } else {
    int tid = threadIdx.x;
    for (int e = tid; e < 3072; e += 256) {
      int j = e & 7;
      int lane = (e >> 3) & 63;
      int idx = e >> 9;  // n2t*3 + ks2
      int ks2 = idx % 3, n2t = idx / 3;
      int n2 = n2t * 16 + (lane & 15);
      int k2 = (ks2 << 5) + ((lane >> 4) << 3) + j;
      int pch = (2 * (k2 >> 5) + ((k2 & 7) >> 2)) * 16 + 4 * ((k2 & 31) >> 3) + (k2 & 3);
      float sc2 = bn2_g[n2] * rsqrtf(bn2_v[n2] + 1e-5f);
      W2_sw[e] = f2bf(w_comb[n2 * 96 + pch] * sc2);
    }
    // zero tails of the 4 x-regions (OOB landing pads)
    {
      int q = tid >> 6, e2 = tid & 63;
      xT2[q * XREG_USH + 524288 + e2] = 0;
    }
    if (tid < 32) {
      float s1 = bn1_g[tid] * rsqrtf(bn1_v[tid] + 1e-5f);
      bias1[tid] = (b_def[tid] - bn1_m[tid]) * s1 + bn1_b[tid];
      float s2 = bn2_g[tid] * rsqrtf(bn2_v[tid] + 1e-5f);
      bias2[tid] = (b_comb[tid] - bn2_m[tid]) * s2 + bn2_b[tid];
    }
  }
}

// ---------------- K1: main fused kernel -------------------------------------
// Grid 1024 blocks, 384 thr (6 waves). bid -> (a,bph) + (8x,4y,4z) tile,
// phase-siblings co-XCD. Wave wv = ntile owner. M=128/block (8 mtiles of 16).
// mtile mt: dz = mt>>1, dy-slab = 2*(mt&1); m=lane&15: ax=m&7, ay=m>>3.
// hi = lane>>4: k-group (x sub-region) in main; k2/ch group in combine.
__launch_bounds__(384, 3)
__global__ void k_main(const unsigned short* __restrict__ xT2,
                       const unsigned short* __restrict__ W_sw,
                       const unsigned short* __restrict__ W2_sw,
                       const float* __restrict__ bias1f,
                       const float* __restrict__ bias2f,
                       float* __restrict__ out) {
  __shared__ unsigned short act[128 * 104];  // 26,624 B, combine-B k2 order
  int tid = threadIdx.x;
  int lane = tid & 63;
  int wv = tid >> 6;  // 0..5 = owned ntile
  int bid = blockIdx.x;
  int tb = (bid & 7) | ((bid >> 5) << 3);  // tile 0..255
  int ph = (bid >> 3) & 3;
  int bph = ph & 1, a = ph >> 1;
  int tx = tb & 3, ty = (tb >> 2) & 7, tz = tb >> 5;
  int i0 = tz * 4, j0 = ty * 4, k0 = tx * 8;

  int m = lane & 15, hi = lane >> 4;
  int ax = m & 7, ay = m >> 3;
  int p0 = (a << 2) | (bph << 1);
  const char* xb0 = (const char*)xT2 + (size_t)(hi >> 1) * 1048704 + ((hi & 1) << 4);

  // per-wave BN1 bias (ntile wv, lane group hi)
  float b1r[4];
#pragma unroll
  for (int r = 0; r < 4; ++r) b1r[r] = bias1f[(wv * 16 + 4 * hi + r) & 31];
  // combine-side BN2 bias (waves 0-3 use it)
  f32x4 b2v[2];
#pragma unroll
  for (int r = 0; r < 4; ++r) {
    b2v[0][r] = bias2f[4 * hi + r];
    b2v[1][r] = bias2f[16 + 4 * hi + r];
  }
  int colbase = 32 * (wv >> 1) + 8 * hi + 4 * (wv & 1);  // act column base

  const uint4* w2q = (const uint4*)W2_sw;
  f32x4 osv[2][2];  // [sub][n2t] cp=0 results

#pragma unroll
  for (int cp = 0; cp < 2; ++cp) {
    const uint4* wp = (const uint4*)(W_sw + (size_t)(p0 | cp) * 49152) + wv * 64 + lane;
    f32x4 acc[8];
#pragma unroll
    for (int mt = 0; mt < 8; ++mt) acc[mt] = (f32x4)0.f;

    // ---- sync-free main loop: 16 ksteps x {1 w-load, 8 x-loads, 8 MFMA} ----
#pragma unroll
    for (int ks = 0; ks < 16; ++ks) {
      int tap = ks >> 1, khalf = ks & 1;
      int jz = (tap >> 2) & 1, jy = (tap >> 1) & 1, jx = tap & 1;
      const char* xp = xb0 + khalf * 2097408;
      int gx = k0 + ax + cp - 1 + jx;
      bool okx = (unsigned)gx < 32u;
      unsigned xo[8];
#pragma unroll
      for (int mt = 0; mt < 8; ++mt) {
        int gz = i0 + (mt >> 1) + a - 1 + jz;
        int gy = j0 + 2 * (mt & 1) + ay + bph - 1 + jy;
        bool ok = okx && ((unsigned)gz < 32u) && ((unsigned)gy < 32u);
        unsigned off = (unsigned)(((gz * 32 + gy) * 32 + gx) * 32);
        xo[mt] = ok ? off : XZERO_B;
      }
      bf16x8 wfr = bc16(wp[ks * 384]);
#pragma unroll
      for (int mt = 0; mt < 8; ++mt) {
        bf16x8 xf = bc16(*(const uint4*)(xp + xo[mt]));
        acc[mt] = __builtin_amdgcn_mfma_f32_16x16x32_bf16(wfr, xf, acc[mt], 0, 0, 0);
      }
    }

    // ---- epilogue: BN1+ReLU pack -> act LDS (combine-B k2 order) ----
    if (cp == 1) __syncthreads();  // cp0 combine reads done before overwrite
#pragma unroll
    for (int mt = 0; mt < 8; ++mt) {
      int sp = 16 * mt + m;
      unsigned d0 = cvtpk(fmaxf(acc[mt][0] + b1r[0], 0.f),
                          fmaxf(acc[mt][1] + b1r[1], 0.f));
      unsigned d1 = cvtpk(fmaxf(acc[mt][2] + b1r[2], 0.f),
                          fmaxf(acc[mt][3] + b1r[3], 0.f));
      *(uint2*)(act + sp * 104 + colbase) = make_uint2(d0, d1);
    }
    __syncthreads();

    // ---- combine GEMM (waves 0-3; wave w handles mtiles {w, w+4}) ----
    if (wv < 4) {
#pragma unroll
      for (int sub = 0; sub < 2; ++sub) {
        int mt = wv + 4 * sub;
        int sp = 16 * mt + m;
        const unsigned short* ab = act + sp * 104 + 8 * hi;
        uint4 fr0 = *(const uint4*)(ab);
        uint4 fr1 = *(const uint4*)(ab + 32);
        uint4 fr2 = *(const uint4*)(ab + 64);
        f32x4 a20 = (f32x4)0.f, a21 = (f32x4)0.f;
        a20 = __builtin_amdgcn_mfma_f32_16x16x32_bf16(bc16(w2q[0 * 64 + lane]), bc16(fr0), a20, 0, 0, 0);
        a20 = __builtin_amdgcn_mfma_f32_16x16x32_bf16(bc16(w2q[1 * 64 + lane]), bc16(fr1), a20, 0, 0, 0);
        a20 = __builtin_amdgcn_mfma_f32_16x16x32_bf16(bc16(w2q[2 * 64 + lane]), bc16(fr2), a20, 0, 0, 0);
        a21 = __builtin_amdgcn_mfma_f32_16x16x32_bf16(bc16(w2q[3 * 64 + lane]), bc16(fr0), a21, 0, 0, 0);
        a21 = __builtin_amdgcn_mfma_f32_16x16x32_bf16(bc16(w2q[4 * 64 + lane]), bc16(fr1), a21, 0, 0, 0);
        a21 = __builtin_amdgcn_mfma_f32_16x16x32_bf16(bc16(w2q[5 * 64 + lane]), bc16(fr2), a21, 0, 0, 0);
        if (cp == 0) {
#pragma unroll
          for (int r = 0; r < 4; ++r) {
            osv[sub][0][r] = fmaxf(a20[r] + b2v[0][r], 0.f);
            osv[sub][1][r] = fmaxf(a21[r] + b2v[1][r], 0.f);
          }
        } else {
          int Z = 2 * (i0 + (mt >> 1)) + a;
          int Y = 2 * (j0 + 2 * (mt & 1) + ay) + bph;
          size_t sb = ((size_t)Z << 11) + (Y << 5) + (k0 + ax);
          float2* o2 = (float2*)out;
#pragma unroll
          for (int r = 0; r < 4; ++r) {
            int ch0 = 4 * hi + r, ch1 = 16 + 4 * hi + r;
            o2[((size_t)ch0 << 17) + sb] =
                make_float2(osv[sub][0][r], fmaxf(a20[r] + b2v[0][r], 0.f));
            o2[((size_t)ch1 << 17) + sb] =
                make_float2(osv[sub][1][r], fmaxf(a21[r] + b2v[1][r], 0.f));
          }
        }
      }
    }
  }
}

// ---------------------------------------------------------------------------
extern "C" void kernel_launch(void* const* d_in, const int* in_sizes, int n_in,
                              void* d_out, int out_size, void* d_ws, size_t ws_size,
                              hipStream_t stream) {
  (void)in_sizes; (void)n_in; (void)out_size; (void)ws_size;
  const float* x      = (const float*)d_in[0];
  const float* w_def  = (const float*)d_in[1];
  const float* b_def  = (const float*)d_in[2];
  const float* bn1_g  = (const float*)d_in[3];
  const float* bn1_b  = (const float*)d_in[4];
  const float* bn1_m  = (const float*)d_in[5];
  const float* bn1_v  = (const float*)d_in[6];
  const float* w_comb = (const float*)d_in[7];
  const float* b_comb = (const float*)d_in[8];
  const float* bn2_g  = (const float*)d_in[9];
  const float* bn2_b  = (const float*)d_in[10];
  const float* bn2_m  = (const float*)d_in[11];
  const float* bn2_v  = (const float*)d_in[12];

  char* ws = (char*)d_ws;
  unsigned short* xT2  = (unsigned short*)(ws);             // 4,194,816 B
  unsigned short* W_sw = (unsigned short*)(ws + 4194816);   //   786,432 B
  unsigned short* W2sw = (unsigned short*)(ws + 4981248);   //     6,144 B
  float* bias1 = (float*)(ws + 4987392);                    //       128 B
  float* bias2 = (float*)(ws + 4987520);                    //       128 B
  float* out = (float*)d_out;

  hipLaunchKernelGGL(k_prep, dim3(2049), dim3(256), 0, stream,
                     x, xT2, w_def, bn1_g, bn1_v, W_sw,
                     w_comb, b_comb, bn2_g, bn2_b, bn2_m, bn2_v,
                     b_def, bn1_b, bn1_m, W2sw, bias1, bias2);
  hipLaunchKernelGGL(k_main, dim3(1024), dim3(384), 0, stream,
                     xT2, W_sw, W2sw, bias1, bias2, out);
}

// Round 10
// 80.237 us; speedup vs baseline: 3.5673x; 3.5673x over previous
//
#include <hip/hip_runtime.h>

// ---------------------------------------------------------------------------
// UpThreeOffsetsConvShareWeights v11: barrier-free v7 (32x32, all-L2 streams).
//
// Algebra unchanged: separable deform offsets -> per-phase 2x2x2-tap conv ==
// GEMM M=spatial x N=96 x K=512, fused K=96 combine GEMM. C^T convention
// (mfma(W_frag, x_frag), lane&31 = spatial col), 32x32x16 MFMA with the
// v5/v6/v7-proven W_sw/W2_sw layouts and v7's proven cvt_pk+permlane epilogue
// and full-line float2 stores. x from the v8-proven 4-region xT2 layout
// (16-ch bricks, zero-tail OOB redirect).
//
// Evidence: v5-v8 (LDS ring + lockstep barriers) all 44-48us, every pipe
// <=25% -- sync/latency bound at 2 waves/SIMD. v9 (barrier-free) failed on
// 2-wave blocks (weight dedup x2 -> 786MB L2) + shallow pipelining. v10
// (M=128/wave) died of register spill (510MB scratch writes). v11:
//  * mt=1/wave: acc 48 + osv 16 regs -> ~3 waves/SIMD, no spill risk.
//  * NO LDS / NO barriers in the main loop; weights straight from L2;
//    8-wave blocks so all waves share the same 96KB/phase weight stream
//    via L1 (dedup x8). One token s_barrier per cp bounds wave drift.
//  * per q-step: 3 w-loads + 1 x-load + 3 MFMA (independent acc chains).
//  * grid 512 x 512thr; tile (8x,4y,8z) x (a,bph); phase-siblings co-XCD.
// ---------------------------------------------------------------------------

typedef __bf16 bf16x8 __attribute__((ext_vector_type(8)));
typedef float f32x16 __attribute__((ext_vector_type(16)));
typedef unsigned u32x2 __attribute__((ext_vector_type(2)));

__device__ inline unsigned short f2bf(float f) {
  unsigned int u = __float_as_uint(f);
  u += 0x7FFFu + ((u >> 16) & 1u);
  return (unsigned short)(u >> 16);
}

__device__ inline bf16x8 bc16(uint4 v) { return __builtin_bit_cast(bf16x8, v); }

__device__ inline unsigned cvtpk(float lo, float hi) {
  unsigned r;
  asm("v_cvt_pk_bf16_f32 %0, %1, %2" : "=v"(r) : "v"(lo), "v"(hi));
  return r;
}

__device__ inline void plswap(unsigned& a, unsigned& b) {
  u32x2 r = __builtin_amdgcn_permlane32_swap(a, b, false, false);
  a = r.x;
  b = r.y;
}

__device__ inline float ucoef(int abit, int k, int jbit, float alpha) {
  if (abit == 0) return (k == 0) ? (jbit ? alpha : 1.f - alpha) : (jbit ? 1.f : 0.f);
  return (k == 2) ? (jbit ? 1.f - alpha : alpha) : (jbit ? 0.f : 1.f);
}

// xT2: 4 regions (16-ch groups), each 32768 sp * 32 B + 128 B zero tail.
#define XREG_USH 524352   // region stride in ushorts (1,048,704 B)
#define XREG_B 1048704    // region stride in bytes
#define XZERO_B 1048576u  // zero-tail byte offset within a region

// ---------------- K0: all preprocessing in one kernel (2049 blocks) ---------
// W_sw (32x32x16 layout, v5-proven): e = ((p*32+s)*3+nt)*512 + lane*8 + j
//   value = B[kk = 16s + 8*(lane>>5) + j][n = nt*32 + (lane&31)]
// W2_sw (v5-proven): e = (s2*64+lane)*8+j, B2[16s2+8*(lane>>5)+j][lane&31]
__global__ void k_prep(const float* __restrict__ x, unsigned short* __restrict__ xT2,
                       const float* __restrict__ w_def, const float* __restrict__ bn1_g,
                       const float* __restrict__ bn1_v, unsigned short* __restrict__ W_sw,
                       const float* __restrict__ w_comb, const float* __restrict__ b_comb,
                       const float* __restrict__ bn2_g, const float* __restrict__ bn2_b,
                       const float* __restrict__ bn2_m, const float* __restrict__ bn2_v,
                       const float* __restrict__ b_def, const float* __restrict__ bn1_b,
                       const float* __restrict__ bn1_m, unsigned short* __restrict__ W2_sw,
                       float* __restrict__ bias1, float* __restrict__ bias2) {
  __shared__ unsigned short t[64][65];
  int bid = blockIdx.x;
  if (bid < 512) {
    int s0 = bid * 64;
    int lane = threadIdx.x & 63;
    int grp = threadIdx.x >> 6;
#pragma unroll
    for (int c = grp; c < 64; c += 4)
      t[c][lane] = f2bf(x[c * 32768 + s0 + lane]);
    __syncthreads();
    int q = lane >> 4, e = lane & 15;  // channel = 16q + e
#pragma unroll
    for (int s = grp; s < 64; s += 4)
      xT2[q * XREG_USH + (size_t)(s0 + s) * 16 + e] = t[lane][s];
  } else if (bid < 2048) {
    int e = (bid - 512) * 256 + threadIdx.x;  // < 393216
    int j = e & 7;
    int lane = (e >> 3) & 63;
    int idx = e >> 9;
    int nt = idx % 3;
    idx /= 3;
    int s = idx & 31;
    int p = idx >> 5;
    int o = lane & 31;
    int br = nt;
    int kk = 16 * s + ((lane >> 5) << 3) + j;
    int tap = kk >> 6, ch = kk & 63;
    int jz = (tap >> 2) & 1, jy = (tap >> 1) & 1, jx = tap & 1;
    int a = (p >> 2) & 1, b = (p >> 1) & 1, cp = p & 1;
    float alpha = (br == 0) ? 0.f : ((br == 1) ? 0.4f : 0.7f);
    const float* wb = w_def + (o * 64 + ch) * 27;
    float sum = 0.f;
    for (int kz = 0; kz < 3; ++kz) {
      float uz = ucoef(a, kz, jz, alpha);
      if (uz == 0.f) continue;
      for (int ky = 0; ky < 3; ++ky) {
        float uy = ucoef(b, ky, jy, alpha);
        if (uy == 0.f) continue;
        float uzy = uz * uy;
        for (int kx = 0; kx < 3; ++kx) {
          float ux = ucoef(cp, kx, jx, alpha);
          if (ux != 0.f) sum += wb[kz * 9 + ky * 3 + kx] * uzy * ux;
        }
      }
    }
    float s1 = bn1_g[o] * rsqrtf(bn1_v[o] + 1e-5f);
    W_sw[e] = f2bf(sum * s1);
  } else {
    int tid = threadIdx.x;
    for (int e = tid; e < 3072; e += 256) {
      int j = e & 7;
      int lane = (e >> 3) & 63;
      int s2 = e >> 9;
      int n = lane & 31;
      int k = 16 * s2 + ((lane >> 5) << 3) + j;
      float sc2 = bn2_g[n] * rsqrtf(bn2_v[n] + 1e-5f);
      W2_sw[e] = f2bf(w_comb[n * 96 + k] * sc2);
    }
    // zero tails of the 4 x-regions (OOB landing pads)
    {
      int q = tid >> 6, e2 = tid & 63;
      xT2[q * XREG_USH + 524288 + e2] = 0;
    }
    if (tid < 32) {
      float s1 = bn1_g[tid] * rsqrtf(bn1_v[tid] + 1e-5f);
      bias1[tid] = (b_def[tid] - bn1_m[tid]) * s1 + bn1_b[tid];
      float s2 = bn2_g[tid] * rsqrtf(bn2_v[tid] + 1e-5f);
      bias2[tid] = (b_comb[tid] - bn2_m[tid]) * s2 + bn2_b[tid];
    }
  }
}

// ---------------- K1: main fused kernel -------------------------------------
// Grid 512 blocks, 512 thr (8 waves). bid -> (a,bph) + (8x,4y,8z) tile,
// phase-siblings co-XCD. Wave wv: zs=wv>>1 (z pair), ys=wv&1 (y pair).
// M=32/wave: m=lane&31 -> ax=m&7, ay=(m>>3)&1, az=(m>>4)&1; h=lane>>5.
// acc[3nt] f32x16: C^T row(ch) = (reg&3)+8*(reg>>2)+4h, col = m.
__launch_bounds__(512, 3)
__global__ void k_main(const unsigned short* __restrict__ xT2,
                       const unsigned short* __restrict__ W_sw,
                       const unsigned short* __restrict__ W2_sw,
                       const float* __restrict__ bias1f,
                       const float* __restrict__ bias2f,
                       float* __restrict__ out) {
  int tid = threadIdx.x;
  int lane = tid & 63;
  int wv = tid >> 6;  // 0..7
  int bid = blockIdx.x;
  int tb = (bid & 7) | ((bid >> 5) << 3);  // tile 0..127
  int ph = (bid >> 3) & 3;
  int bph = ph & 1, a = ph >> 1;
  int tx = tb & 3, ty = (tb >> 2) & 7, tz = tb >> 5;  // 4 x 8 x 4
  int i0 = tz * 8, j0 = ty * 4, k0 = tx * 8;

  int m = lane & 31, h = lane >> 5;
  int ax = m & 7, ay = (m >> 3) & 1, az = (m >> 4) & 1;
  int zs = wv >> 1, ys = wv & 1;
  int zin = i0 + 2 * zs + az;      // input z of this lane
  int yin = j0 + 2 * ys + ay;      // input y
  int p0 = (a << 2) | (bph << 1);
  const char* xbase = (const char*)xT2 + (h << 4);  // + q*XREG_B + sp*32

  f32x16 osv0;  // cp=0 result (post BN2+ReLU), held across cp=1

#pragma unroll
  for (int cp = 0; cp < 2; ++cp) {
    const uint4* wq = (const uint4*)W_sw + (p0 | cp) * 6144 + lane;
    f32x16 acc[3];
#pragma unroll
    for (int nt = 0; nt < 3; ++nt) acc[nt] = (f32x16)0.f;

#pragma unroll
    for (int tap = 0; tap < 8; ++tap) {
      int jz = (tap >> 2) & 1, jy = (tap >> 1) & 1, jx = tap & 1;
      int gz = zin + a - 1 + jz;
      int gy = yin + bph - 1 + jy;
      int gx = k0 + ax + cp - 1 + jx;
      bool ok = ((unsigned)gz < 32u) && ((unsigned)gy < 32u) && ((unsigned)gx < 32u);
      unsigned xo = ok ? (unsigned)(((gz * 32 + gy) * 32 + gx) * 32) : XZERO_B;
#pragma unroll
      for (int q = 0; q < 4; ++q) {
        int s = tap * 4 + q;
        bf16x8 xf = bc16(*(const uint4*)(xbase + q * XREG_B + xo));
        const uint4* wf = wq + s * 192;
        bf16x8 bb0 = bc16(wf[0]);
        bf16x8 bb1 = bc16(wf[64]);
        bf16x8 bb2 = bc16(wf[128]);
        acc[0] = __builtin_amdgcn_mfma_f32_32x32x16_bf16(bb0, xf, acc[0], 0, 0, 0);
        acc[1] = __builtin_amdgcn_mfma_f32_32x32x16_bf16(bb1, xf, acc[1], 0, 0, 0);
        acc[2] = __builtin_amdgcn_mfma_f32_32x32x16_bf16(bb2, xf, acc[2], 0, 0, 0);
      }
    }

    // token per-cp re-convergence barrier (keeps L1 weight dedup tight)
    __builtin_amdgcn_s_barrier();

    // ---- epilogue: BN1+ReLU, in-reg cvt_pk+permlane relayout, combine ----
    uint4 fr[6];
#pragma unroll
    for (int nt = 0; nt < 3; ++nt) {
      unsigned ww[8];
#pragma unroll
      for (int qc = 0; qc < 8; ++qc) {
        int q = qc >> 1, c2 = qc & 1;
        int r0 = 4 * q + 2 * c2;
        int row = (r0 & 3) + ((r0 >> 2) << 3) + (h << 2);
        float lo = fmaxf(acc[nt][r0] + bias1f[row], 0.f);
        float hi = fmaxf(acc[nt][r0 + 1] + bias1f[row + 1], 0.f);
        ww[2 * q + c2] = cvtpk(lo, hi);
      }
      plswap(ww[0], ww[2]);
      plswap(ww[1], ww[3]);
      plswap(ww[4], ww[6]);
      plswap(ww[5], ww[7]);
      fr[2 * nt] = make_uint4(ww[0], ww[1], ww[2], ww[3]);
      fr[2 * nt + 1] = make_uint4(ww[4], ww[5], ww[6], ww[7]);
    }
    const uint4* w2q = (const uint4*)W2_sw + lane;
    f32x16 acc2 = (f32x16)0.f;
#pragma unroll
    for (int s2 = 0; s2 < 6; ++s2)
      acc2 = __builtin_amdgcn_mfma_f32_32x32x16_bf16(bc16(w2q[s2 * 64]), bc16(fr[s2]),
                                                     acc2, 0, 0, 0);
    if (cp == 0) {
#pragma unroll
      for (int r = 0; r < 16; ++r) {
        int row = (r & 3) + ((r >> 2) << 3) + (h << 2);
        osv0[r] = fmaxf(acc2[r] + bias2f[row], 0.f);
      }
    } else {
      int Z = 2 * zin + a;
      int Y = 2 * yin + bph;
      float2* o2 = (float2*)out;
#pragma unroll
      for (int r = 0; r < 16; ++r) {
        int ch = (r & 3) + ((r >> 2) << 3) + (h << 2);
        float v1 = fmaxf(acc2[r] + bias2f[ch], 0.f);
        o2[((size_t)ch << 17) + ((size_t)Z << 11) + (Y << 5) + (k0 + ax)] =
            make_float2(osv0[r], v1);
      }
    }
  }
}

// ---------------------------------------------------------------------------
extern "C" void kernel_launch(void* const* d_in, const int* in_sizes, int n_in,
                              void* d_out, int out_size, void* d_ws, size_t ws_size,
                              hipStream_t stream) {
  (void)in_sizes; (void)n_in; (void)out_size; (void)ws_size;
  const float* x      = (const float*)d_in[0];
  const float* w_def  = (const float*)d_in[1];
  const float* b_def  = (const float*)d_in[2];
  const float* bn1_g  = (const float*)d_in[3];
  const float* bn1_b  = (const float*)d_in[4];
  const float* bn1_m  = (const float*)d_in[5];
  const float* bn1_v  = (const float*)d_in[6];
  const float* w_comb = (const float*)d_in[7];
  const float* b_comb = (const float*)d_in[8];
  const float* bn2_g  = (const float*)d_in[9];
  const float* bn2_b  = (const float*)d_in[10];
  const float* bn2_m  = (const float*)d_in[11];
  const float* bn2_v  = (const float*)d_in[12];

  char* ws = (char*)d_ws;
  unsigned short* xT2  = (unsigned short*)(ws);             // 4,194,816 B
  unsigned short* W_sw = (unsigned short*)(ws + 4194816);   //   786,432 B
  unsigned short* W2sw = (unsigned short*)(ws + 4981248);   //     6,144 B
  float* bias1 = (float*)(ws + 4987392);                    //       128 B
  float* bias2 = (float*)(ws + 4987520);                    //       128 B
  float* out = (float*)d_out;

  hipLaunchKernelGGL(k_prep, dim3(2049), dim3(256), 0, stream,
                     x, xT2, w_def, bn1_g, bn1_v, W_sw,
                     w_comb, b_comb, bn2_g, bn2_b, bn2_m, bn2_v,
                     b_def, bn1_b, bn1_m, W2sw, bias1, bias2);
  hipLaunchKernelGGL(k_main, dim3(512), dim3(512), 0, stream,
                     xT2, W_sw, W2sw, bias1, bias2, out);
}

// Round 11
// 52.654 us; speedup vs baseline: 5.4360x; 1.5239x over previous
//
#include <hip/hip_runtime.h>

// ---------------------------------------------------------------------------
// UpThreeOffsetsConvShareWeights v12: v6 structure + depth-2 COUNTED vmcnt ring.
//
// Same algebra (separable deform offsets -> per-phase 2x2x2-tap conv == GEMM
// M=spatial x N=96 x K=512; fused K=96 combine GEMM), C^T convention
// (mfma(W_frag, x_frag), lane&31 = spatial col), 32x32x16 MFMA, v6-proven
// layouts (xT[sp][64], rotated xt LDS tile, W_sw/W2_sw, cvt_pk+permlane
// epilogue, full-line float2 stores).
//
// Evidence recap: v6 (drain-0 ring) = 48us k_main, all pipes <=25% -- waves
// drain at every sync. T3+T4 (counted vmcnt: loads stay in flight ACROSS
// barriers) is the one measured lever for exactly this plateau (+38-73% vs
// drain-0, learn_hip m218), but requires the loop's ONLY VMEM to be ring
// loads. v6 satisfies this: xt staged before the loop (drained by
// __syncthreads), biases/b2f pre-loaded, epilogues VMEM-free, no spills.
// v12 changes vs v6 (minimal, schedule-only):
//  * ring: 3 slots x 12KB (1-tap chunks), 16 chunks (c = cp*8 + tap).
//  * steady state: wait vmcnt(2) [chunk c landed, c+1 flying] -> s_barrier
//    -> stage(c+2) -> 24 MFMAs. Loads NEVER drain to 0 until the tail.
//  * slot (c+2)%3 overwrites chunk c-1: all waves passed this barrier =>
//    all finished computing c-1. Tail: c=14 waits (2), c=15 waits (0).
//  * LDS: xt 101.25 + ring 36 + bias 0.25 = 137.5 KB, 1 block/CU, 8 waves.
// ---------------------------------------------------------------------------

typedef __bf16 bf16x8 __attribute__((ext_vector_type(8)));
typedef float f32x16 __attribute__((ext_vector_type(16)));
typedef unsigned u32x2 __attribute__((ext_vector_type(2)));

__device__ inline unsigned short f2bf(float f) {
  unsigned int u = __float_as_uint(f);
  u += 0x7FFFu + ((u >> 16) & 1u);
  return (unsigned short)(u >> 16);
}

__device__ inline bf16x8 bc16(uint4 v) { return __builtin_bit_cast(bf16x8, v); }

__device__ inline unsigned cvtpk(float lo, float hi) {
  unsigned r;
  asm("v_cvt_pk_bf16_f32 %0, %1, %2" : "=v"(r) : "v"(lo), "v"(hi));
  return r;
}

__device__ inline void plswap(unsigned& a, unsigned& b) {
  u32x2 r = __builtin_amdgcn_permlane32_swap(a, b, false, false);
  a = r.x;
  b = r.y;
}

__device__ inline void gload16(const unsigned short* g, unsigned short* l) {
  __builtin_amdgcn_global_load_lds(
      (const __attribute__((address_space(1))) unsigned int*)(const void*)g,
      (__attribute__((address_space(3))) unsigned int*)(void*)l, 16, 0, 0);
}

__device__ inline float ucoef(int abit, int k, int jbit, float alpha) {
  if (abit == 0) return (k == 0) ? (jbit ? alpha : 1.f - alpha) : (jbit ? 1.f : 0.f);
  return (k == 2) ? (jbit ? 1.f - alpha : alpha) : (jbit ? 0.f : 1.f);
}

// ---------------- K0: all preprocessing in one kernel (2049 blocks) ---------
// (byte-identical to v5/v6's proven k_prep)
__global__ void k_prep(const float* __restrict__ x, unsigned short* __restrict__ xT,
                       const float* __restrict__ w_def, const float* __restrict__ bn1_g,
                       const float* __restrict__ bn1_v, unsigned short* __restrict__ W_sw,
                       const float* __restrict__ w_comb, const float* __restrict__ b_comb,
                       const float* __restrict__ bn2_g, const float* __restrict__ bn2_b,
                       const float* __restrict__ bn2_m, const float* __restrict__ bn2_v,
                       const float* __restrict__ b_def, const float* __restrict__ bn1_b,
                       const float* __restrict__ bn1_m, unsigned short* __restrict__ W2_sw,
                       float* __restrict__ bias1, float* __restrict__ bias2) {
  __shared__ unsigned short t[64][65];
  int bid = blockIdx.x;
  if (bid < 512) {
    int s0 = bid * 64;
    int lane = threadIdx.x & 63;
    int grp = threadIdx.x >> 6;
#pragma unroll
    for (int c = grp; c < 64; c += 4)
      t[c][lane] = f2bf(x[c * 32768 + s0 + lane]);
    __syncthreads();
#pragma unroll
    for (int s = grp; s < 64; s += 4)
      xT[(size_t)(s0 + s) * 64 + lane] = t[lane][s];
  } else if (bid < 2048) {
    int e = (bid - 512) * 256 + threadIdx.x;  // < 393216
    int j = e & 7;
    int lane = (e >> 3) & 63;
    int idx = e >> 9;
    int nt = idx % 3;
    idx /= 3;
    int s = idx & 31;
    int p = idx >> 5;
    int o = lane & 31;
    int br = nt;
    int kk = 16 * s + ((lane >> 5) << 3) + j;
    int tap = kk >> 6, ch = kk & 63;
    int jz = (tap >> 2) & 1, jy = (tap >> 1) & 1, jx = tap & 1;
    int a = (p >> 2) & 1, b = (p >> 1) & 1, cp = p & 1;
    float alpha = (br == 0) ? 0.f : ((br == 1) ? 0.4f : 0.7f);
    const float* wb = w_def + (o * 64 + ch) * 27;
    float sum = 0.f;
    for (int kz = 0; kz < 3; ++kz) {
      float uz = ucoef(a, kz, jz, alpha);
      if (uz == 0.f) continue;
      for (int ky = 0; ky < 3; ++ky) {
        float uy = ucoef(b, ky, jy, alpha);
        if (uy == 0.f) continue;
        float uzy = uz * uy;
        for (int kx = 0; kx < 3; ++kx) {
          float ux = ucoef(cp, kx, jx, alpha);
          if (ux != 0.f) sum += wb[kz * 9 + ky * 3 + kx] * uzy * ux;
        }
      }
    }
    float s1 = bn1_g[o] * rsqrtf(bn1_v[o] + 1e-5f);
    W_sw[e] = f2bf(sum * s1);
  } else {
    int tid = threadIdx.x;
    for (int e = tid; e < 3072; e += 256) {
      int j = e & 7;
      int lane = (e >> 3) & 63;
      int s2 = e >> 9;
      int n = lane & 31;
      int k = 16 * s2 + ((lane >> 5) << 3) + j;
      float sc2 = bn2_g[n] * rsqrtf(bn2_v[n] + 1e-5f);
      W2_sw[e] = f2bf(w_comb[n * 96 + k] * sc2);
    }
    if (tid < 32) {
      float s1 = bn1_g[tid] * rsqrtf(bn1_v[tid] + 1e-5f);
      bias1[tid] = (b_def[tid] - bn1_m[tid]) * s1 + bn1_b[tid];
      float s2 = bn2_g[tid] * rsqrtf(bn2_v[tid] + 1e-5f);
      bias2[tid] = (b_comb[tid] - bn2_m[tid]) * s2 + bn2_b[tid];
    }
  }
}

// ---------------- K1: main fused kernel -------------------------------------
// Grid 256 blocks (1/CU), 512 thr (8 waves). bid -> (a,bph) + 8x8x8 tile.
// Wave wv: zs=wv>>2, ys=wv&3. Per wave M=64 (2 mt x 32 m), cp = chunk>>3.
__launch_bounds__(512, 2)
__global__ void k_main(const unsigned short* __restrict__ xT,
                       const unsigned short* __restrict__ W_sw,
                       const unsigned short* __restrict__ W2_sw,
                       const float* __restrict__ bias1f,
                       const float* __restrict__ bias2f,
                       float* __restrict__ out) {
  __shared__ unsigned short xt[51840];       // 9*9*10 rows * 64 ch (101.25 KB)
  __shared__ unsigned short wring[3][6144];  // 3 slots * 12 KB (1 tap each)
  __shared__ float blds[64];                 // bias1 | bias2 tables
  int tid = threadIdx.x;
  int lane = tid & 63;
  int wv = tid >> 6;
  int bid = blockIdx.x;
  int bph = bid & 1, a = (bid >> 1) & 1;
  int tb = bid >> 2;
  int tx = tb & 3, ty = (tb >> 2) & 3, tz = tb >> 4;
  int i0 = tz * 8, j0 = ty * 8, k0 = tx * 8;

  // ---- stage xt (halo 1; z-origin shifted by a, y-origin by bph) ----
  for (int t2 = tid; t2 < 6480; t2 += 512) {  // 810 rows * 8 ch-blocks
    int cblk = t2 & 7;
    int r = t2 >> 3;  // row = (zrel*9 + yrel)*10 + xrel
    int xrel = r % 10;
    int zy = r / 10;
    int yrel = zy % 9;
    int zrel = zy / 9;
    int gz = i0 + a - 1 + zrel, gy = j0 + bph - 1 + yrel, gx = k0 - 1 + xrel;
    uint4 v = make_uint4(0u, 0u, 0u, 0u);
    if ((unsigned)gz < 32u && (unsigned)gy < 32u && (unsigned)gx < 32u)
      v = *(const uint4*)(xT + ((((gz * 32 + gy) * 32 + gx) << 6) + (cblk << 3)));
    *(uint4*)(xt + ((r << 6) + (((cblk + r) << 3) & 63))) = v;
  }
  if (tid < 32) {
    blds[tid] = bias1f[tid];
    blds[32 + tid] = bias2f[tid];
  }

  // combine weights in registers (loaded before the big sync)
  bf16x8 b2f[6];
  const uint4* w2q = (const uint4*)W2_sw;
#pragma unroll
  for (int s2 = 0; s2 < 6; ++s2) b2f[s2] = bc16(w2q[s2 * 64 + lane]);
  __syncthreads();  // drains ALL pre-loop VMEM: vmcnt==0 from here

  int h = lane >> 5, h8 = h << 3;
  int m = lane & 31;
  int ax = m & 7, ay = (m >> 3) & 1, az = m >> 4;
  int zs = wv >> 2, ys = wv & 3;
  int dz0 = 4 * zs + az;  // + 2*mt
  int dy = 2 * ys + ay;
  int p0 = (a << 2) | (bph << 1);

  // chunk c (0..15): phase p0|(c>>3), tap c&7 (12288 B). Waves 0-5 stage
  // 2048 B each as 2 x width-16 wave-instructions; waves 6-7 idle (their
  // vmcnt is trivially satisfied; the barrier hands them the data).
  auto stage = [&](int c, int slot) {
    if (wv < 6) {
      int pn = p0 | (c >> 3);
      const unsigned short* g =
          W_sw + (size_t)pn * 49152 + (c & 7) * 6144 + wv * 1024 + lane * 8;
      unsigned short* l = &wring[slot][wv * 1024];
      gload16(g, l);
      gload16(g + 512, l + 512);
    }
  };

  stage(0, 0);  // prologue: 2 chunks in flight
  stage(1, 1);

  f32x16 osv0, osv1;  // cp=0 results, held across cp=1
  f32x16 acc[2][3];
#pragma unroll
  for (int mt = 0; mt < 2; ++mt)
#pragma unroll
    for (int nt = 0; nt < 3; ++nt) acc[mt][nt] = (f32x16)0.f;

  for (int c = 0; c < 16; ++c) {
    // counted wait: own chunk-c loads landed; chunk c+1 stays IN FLIGHT.
    if (c < 15) {
      asm volatile("s_waitcnt vmcnt(2)" ::: "memory");
    } else {
      asm volatile("s_waitcnt vmcnt(0)" ::: "memory");
    }
    __builtin_amdgcn_s_barrier();  // all waves' chunk-c parts visible
    __builtin_amdgcn_sched_barrier(0);
    if (c < 14) stage(c + 2, (c + 2) % 3);  // overwrites chunk c-1's slot: safe
    __builtin_amdgcn_sched_barrier(0);

    int cp = c >> 3, t8 = c & 7;
    int jz = (t8 >> 2) & 1, jy = (t8 >> 1) & 1, jx = t8 & 1;
    int row0 = ((dz0 + jz) * 9 + (dy + jy)) * 10 + (ax + cp + jx);
    int row1 = row0 + 180;  // mt=1: z += 2
    const unsigned short* wfb = &wring[c % 3][lane * 8];
#pragma unroll
    for (int q = 0; q < 4; ++q) {  // s = 4*tap + q
      int c0 = (q << 4) + h8;
      int e0 = (row0 << 6) + ((c0 + (row0 << 3)) & 63);
      int e1 = (row1 << 6) + ((c0 + (row1 << 3)) & 63);
      bf16x8 a0 = bc16(*(const uint4*)(xt + e0));
      bf16x8 a1 = bc16(*(const uint4*)(xt + e1));
      const unsigned short* wf = wfb + q * 1536;
      bf16x8 bb0 = bc16(*(const uint4*)(wf));
      bf16x8 bb1 = bc16(*(const uint4*)(wf + 512));
      bf16x8 bb2 = bc16(*(const uint4*)(wf + 1024));
      __builtin_amdgcn_s_setprio(1);
      acc[0][0] = __builtin_amdgcn_mfma_f32_32x32x16_bf16(bb0, a0, acc[0][0], 0, 0, 0);
      acc[1][0] = __builtin_amdgcn_mfma_f32_32x32x16_bf16(bb0, a1, acc[1][0], 0, 0, 0);
      acc[0][1] = __builtin_amdgcn_mfma_f32_32x32x16_bf16(bb1, a0, acc[0][1], 0, 0, 0);
      acc[1][1] = __builtin_amdgcn_mfma_f32_32x32x16_bf16(bb1, a1, acc[1][1], 0, 0, 0);
      acc[0][2] = __builtin_amdgcn_mfma_f32_32x32x16_bf16(bb2, a0, acc[0][2], 0, 0, 0);
      acc[1][2] = __builtin_amdgcn_mfma_f32_32x32x16_bf16(bb2, a1, acc[1][2], 0, 0, 0);
      __builtin_amdgcn_s_setprio(0);
    }

    if (c == 7) {
      // ---- cp=0 epilogue: BN1+ReLU, in-reg relayout, combine, BN2+ReLU ----
      // (no VMEM: keeps the counted-ring discipline intact)
#pragma unroll
      for (int mt = 0; mt < 2; ++mt) {
        uint4 fr[6];
#pragma unroll
        for (int nt = 0; nt < 3; ++nt) {
          unsigned ww[8];
#pragma unroll
          for (int qc = 0; qc < 8; ++qc) {
            int q = qc >> 1, c2 = qc & 1;
            int r0 = 4 * q + 2 * c2;
            int row = (r0 & 3) + ((r0 >> 2) << 3) + (h << 2);
            float lo = fmaxf(acc[mt][nt][r0] + blds[row], 0.f);
            float hi = fmaxf(acc[mt][nt][r0 + 1] + blds[row + 1], 0.f);
            ww[2 * q + c2] = cvtpk(lo, hi);
          }
          plswap(ww[0], ww[2]);
          plswap(ww[1], ww[3]);
          plswap(ww[4], ww[6]);
          plswap(ww[5], ww[7]);
          fr[2 * nt] = make_uint4(ww[0], ww[1], ww[2], ww[3]);
          fr[2 * nt + 1] = make_uint4(ww[4], ww[5], ww[6], ww[7]);
        }
        f32x16 acc2 = (f32x16)0.f;
#pragma unroll
        for (int s2 = 0; s2 < 6; ++s2)
          acc2 = __builtin_amdgcn_mfma_f32_32x32x16_bf16(b2f[s2], bc16(fr[s2]), acc2, 0, 0, 0);
        f32x16 ov;
#pragma unroll
        for (int r = 0; r < 16; ++r) {
          int row = (r & 3) + ((r >> 2) << 3) + (h << 2);
          ov[r] = fmaxf(acc2[r] + blds[32 + row], 0.f);
        }
        if (mt == 0) osv0 = ov; else osv1 = ov;
#pragma unroll
        for (int nt = 0; nt < 3; ++nt) acc[mt][nt] = (f32x16)0.f;
      }
    }
  }

  // ---- cp=1 epilogue: same pipeline + full-line float2 stores ----
#pragma unroll
  for (int mt = 0; mt < 2; ++mt) {
    uint4 fr[6];
#pragma unroll
    for (int nt = 0; nt < 3; ++nt) {
      unsigned ww[8];
#pragma unroll
      for (int qc = 0; qc < 8; ++qc) {
        int q = qc >> 1, c2 = qc & 1;
        int r0 = 4 * q + 2 * c2;
        int row = (r0 & 3) + ((r0 >> 2) << 3) + (h << 2);
        float lo = fmaxf(acc[mt][nt][r0] + blds[row], 0.f);
        float hi = fmaxf(acc[mt][nt][r0 + 1] + blds[row + 1], 0.f);
        ww[2 * q + c2] = cvtpk(lo, hi);
      }
      plswap(ww[0], ww[2]);
      plswap(ww[1], ww[3]);
      plswap(ww[4], ww[6]);
      plswap(ww[5], ww[7]);
      fr[2 * nt] = make_uint4(ww[0], ww[1], ww[2], ww[3]);
      fr[2 * nt + 1] = make_uint4(ww[4], ww[5], ww[6], ww[7]);
    }
    f32x16 acc2 = (f32x16)0.f;
#pragma unroll
    for (int s2 = 0; s2 < 6; ++s2)
      acc2 = __builtin_amdgcn_mfma_f32_32x32x16_bf16(b2f[s2], bc16(fr[s2]), acc2, 0, 0, 0);
    f32x16 prev = (mt == 0) ? osv0 : osv1;
    int Z = 2 * (i0 + 4 * zs + 2 * mt + az) + a;
    int Y = 2 * (j0 + dy) + bph;
    float2* o2 = (float2*)out;
#pragma unroll
    for (int r = 0; r < 16; ++r) {
      int ch = (r & 3) + ((r >> 2) << 3) + (h << 2);
      float v1 = fmaxf(acc2[r] + blds[32 + ch], 0.f);
      o2[((size_t)ch << 17) + ((size_t)Z << 11) + (Y << 5) + (k0 + ax)] =
          make_float2(prev[r], v1);
    }
  }
}

// ---------------------------------------------------------------------------
extern "C" void kernel_launch(void* const* d_in, const int* in_sizes, int n_in,
                              void* d_out, int out_size, void* d_ws, size_t ws_size,
                              hipStream_t stream) {
  (void)in_sizes; (void)n_in; (void)out_size; (void)ws_size;
  const float* x      = (const float*)d_in[0];
  const float* w_def  = (const float*)d_in[1];
  const float* b_def  = (const float*)d_in[2];
  const float* bn1_g  = (const float*)d_in[3];
  const float* bn1_b  = (const float*)d_in[4];
  const float* bn1_m  = (const float*)d_in[5];
  const float* bn1_v  = (const float*)d_in[6];
  const float* w_comb = (const float*)d_in[7];
  const float* b_comb = (const float*)d_in[8];
  const float* bn2_g  = (const float*)d_in[9];
  const float* bn2_b  = (const float*)d_in[10];
  const float* bn2_m  = (const float*)d_in[11];
  const float* bn2_v  = (const float*)d_in[12];

  char* ws = (char*)d_ws;
  unsigned short* xT   = (unsigned short*)(ws);             // 4,194,304 B
  unsigned short* W_sw = (unsigned short*)(ws + 4194304);   //   786,432 B
  unsigned short* W2sw = (unsigned short*)(ws + 4980736);   //     6,144 B
  float* bias1 = (float*)(ws + 4986880);                    //       128 B
  float* bias2 = (float*)(ws + 4987008);                    //       128 B
  float* out = (float*)d_out;

  hipLaunchKernelGGL(k_prep, dim3(2049), dim3(256), 0, stream,
                     x, xT, w_def, bn1_g, bn1_v, W_sw,
                     w_comb, b_comb, bn2_g, bn2_b, bn2_m, bn2_v,
                     b_def, bn1_b, bn1_m, W2sw, bias1, bias2);
  hipLaunchKernelGGL(k_main, dim3(256), dim3(512), 0, stream,
                     xT, W_sw, W2sw, bias1, bias2, out);
}